// Round 1
// baseline (386.164 us; speedup 1.0000x reference)
//
#include <hip/hip_runtime.h>
#include <stdint.h>

#define TPB 256
#define ELEMS_PER_CHUNK 8192   // TPB * 32 elements per chunk
#define MAX_SCORE_BLOCKS 1024

// d_ws float layout:
//  [0]  : encoded x_min (uint32 ordered encoding)
//  [1]  : encoded x_max
//  [16 + 4k] : params float4 {inv_s, s, lo=-zp, hi=15-zp}   (k = 0..127)
//  [528 + k] : new_min[k]
//  [656 + k] : new_max[k]
//  [2048 + b*128 + k] : per-block partial loss sums
#define OFF_PARAMS 16
#define OFF_NMIN   528
#define OFF_NMAX   656
#define OFF_PART   2048

__device__ __forceinline__ uint32_t enc_f32(float f) {
    uint32_t b = __float_as_uint(f);
    return (b & 0x80000000u) ? ~b : (b | 0x80000000u);
}
__device__ __forceinline__ float dec_f32(uint32_t u) {
    uint32_t b = (u & 0x80000000u) ? (u & 0x7fffffffu) : ~u;
    return __uint_as_float(b);
}

__global__ void k_init(uint32_t* W_u) {
    if (threadIdx.x == 0) {
        W_u[0] = 0xFFFFFFFFu;  // min identity (largest encoded)
        W_u[1] = 0x00000000u;  // max identity (smallest encoded)
    }
}

__global__ void k_minmax(const float* __restrict__ x, int n, uint32_t* __restrict__ W_u) {
    int n4 = n >> 2;
    const float4* x4 = (const float4*)x;
    float mn = INFINITY, mx = -INFINITY;
    int idx = blockIdx.x * blockDim.x + threadIdx.x;
    int stride = gridDim.x * blockDim.x;
    for (int i = idx; i < n4; i += stride) {
        float4 v = x4[i];
        mn = fminf(mn, fminf(fminf(v.x, v.y), fminf(v.z, v.w)));
        mx = fmaxf(mx, fmaxf(fmaxf(v.x, v.y), fmaxf(v.z, v.w)));
    }
    for (int i = (n4 << 2) + idx; i < n; i += stride) {
        float v = x[i];
        mn = fminf(mn, v);
        mx = fmaxf(mx, v);
    }
    #pragma unroll
    for (int m = 32; m; m >>= 1) {
        mn = fminf(mn, __shfl_xor(mn, m, 64));
        mx = fmaxf(mx, __shfl_xor(mx, m, 64));
    }
    if ((threadIdx.x & 63) == 0) {
        atomicMin(&W_u[0], enc_f32(mn));
        atomicMax(&W_u[1], enc_f32(mx));
    }
}

// 1 block, 128 threads: candidate k = (i-1)*16 + zp  (i-major, matching reshape(-1))
__global__ void k_params(const uint32_t* __restrict__ W_u, float* __restrict__ W) {
    int k = threadIdx.x;
    if (k >= 128) return;
    float xmin = dec_f32(W_u[0]);
    float xmax = dec_f32(W_u[1]);
    float xrange = xmax - xmin;
    int ii = k >> 4;                       // 0..7  (i = ii+1)
    float zpf = (float)(k & 15);
    float tmp_max = xrange / 8.0f * (float)(ii + 1);
    float tmp_delta = tmp_max / 15.0f;
    float shift = zpf * tmp_delta;
    float new_min = fmaxf(0.0f - shift, xmin);
    float new_max = fminf(tmp_max - shift, xmax);
    float min_neg = fminf(new_min, 0.0f);
    float max_pos = fmaxf(new_max, 0.0f);
    float scale = fmaxf((max_pos - min_neg) / 15.0f, 1e-8f);
    float zp = 0.0f - rintf(min_neg / scale);
    zp = fminf(fmaxf(zp, 0.0f), 15.0f);
    float4 p;
    p.x = 1.0f / scale;      // inv_s
    p.y = scale;             // s
    p.z = 0.0f - zp;         // lo
    p.w = 15.0f - zp;        // hi
    ((float4*)(W + OFF_PARAMS))[k] = p;
    W[OFF_NMIN + k] = new_min;
    W[OFF_NMAX + k] = new_max;
}

__global__ __launch_bounds__(TPB) void k_score(const float* __restrict__ x, int n,
                                               const float* __restrict__ W,
                                               float* __restrict__ part, int nchunks) {
    __shared__ float4 sp[128];
    __shared__ float wsum[4][128];
    int tid = threadIdx.x;
    if (tid < 128) sp[tid] = ((const float4*)(W + OFF_PARAMS))[tid];
    ((float*)wsum)[tid]       = 0.0f;
    ((float*)wsum)[tid + 256] = 0.0f;
    __syncthreads();
    int lane = tid & 63;
    int wv = tid >> 6;

    for (int c = blockIdx.x; c < nchunks; c += gridDim.x) {
        // load 32 elements into registers (coalesced float4)
        float xv[32];
        long base = (long)c * ELEMS_PER_CHUNK;
        #pragma unroll
        for (int j = 0; j < 8; ++j) {
            long e = base + (long)(j * TPB + tid) * 4;
            float4 v;
            if (e + 3 < (long)n) {
                v = *(const float4*)(x + e);
            } else {
                v.x = (e + 0 < (long)n) ? x[e + 0] : 0.0f;   // 0 contributes 0 to every score
                v.y = (e + 1 < (long)n) ? x[e + 1] : 0.0f;
                v.z = (e + 2 < (long)n) ? x[e + 2] : 0.0f;
                v.w = (e + 3 < (long)n) ? x[e + 3] : 0.0f;
            }
            xv[j * 4 + 0] = v.x;
            xv[j * 4 + 1] = v.y;
            xv[j * 4 + 2] = v.z;
            xv[j * 4 + 3] = v.w;
        }
        for (int k = 0; k < 128; ++k) {
            float4 p = sp[k];
            float acc = 0.0f;
            #pragma unroll
            for (int e = 0; e < 32; ++e) {
                float t = xv[e] * p.x;
                float r = rintf(t);                                   // v_rndne_f32
                float cc = __builtin_amdgcn_fmed3f(r, p.z, p.w);      // clamp
                float d = __builtin_fmaf(cc, p.y, -xv[e]);
                acc = __builtin_fmaf(d, d, acc);
            }
            #pragma unroll
            for (int m = 32; m; m >>= 1) acc += __shfl_xor(acc, m, 64);
            if (lane == 0) wsum[wv][k] += acc;
        }
    }
    __syncthreads();
    if (tid < 128) {
        part[(long)blockIdx.x * 128 + tid] =
            (wsum[0][tid] + wsum[1][tid]) + (wsum[2][tid] + wsum[3][tid]);
    }
}

// 1 block, 128 threads: deterministic fixed-order sum over block partials + first-occurrence argmin
__global__ void k_final(const float* __restrict__ W, const float* __restrict__ part,
                        int nblk, float* __restrict__ out) {
    __shared__ float sc[128];
    int k = threadIdx.x;
    if (k < 128) {
        float s0 = 0.0f, s1 = 0.0f, s2 = 0.0f, s3 = 0.0f;
        int b = 0;
        for (; b + 4 <= nblk; b += 4) {
            s0 += part[(long)(b + 0) * 128 + k];
            s1 += part[(long)(b + 1) * 128 + k];
            s2 += part[(long)(b + 2) * 128 + k];
            s3 += part[(long)(b + 3) * 128 + k];
        }
        float s = (s0 + s1) + (s2 + s3);
        for (; b < nblk; ++b) s += part[(long)b * 128 + k];
        sc[k] = s;
    }
    __syncthreads();
    if (k == 0) {
        int best = 0;
        float bs = sc[0];
        for (int j = 1; j < 128; ++j) {
            if (sc[j] < bs) { bs = sc[j]; best = j; }   // strict < == first occurrence
        }
        out[0] = W[OFF_NMIN + best];
        out[1] = W[OFF_NMAX + best];
    }
}

extern "C" void kernel_launch(void* const* d_in, const int* in_sizes, int n_in,
                              void* d_out, int out_size, void* d_ws, size_t ws_size,
                              hipStream_t stream) {
    const float* x = (const float*)d_in[0];
    int n = in_sizes[0];
    float* out = (float*)d_out;
    float* W = (float*)d_ws;
    uint32_t* W_u = (uint32_t*)d_ws;

    int nchunks = (n + ELEMS_PER_CHUNK - 1) / ELEMS_PER_CHUNK;
    long maxblk_l = ((long)(ws_size / 4) - OFF_PART) / 128;
    int nblk = nchunks < MAX_SCORE_BLOCKS ? nchunks : MAX_SCORE_BLOCKS;
    if (maxblk_l < (long)nblk) nblk = (int)(maxblk_l < 1 ? 1 : maxblk_l);
    if (nblk < 1) nblk = 1;

    k_init<<<1, 64, 0, stream>>>(W_u);

    int n4 = n >> 2;
    int mmblk = (n4 + TPB - 1) / TPB;
    if (mmblk > 2048) mmblk = 2048;
    if (mmblk < 1) mmblk = 1;
    k_minmax<<<mmblk, TPB, 0, stream>>>(x, n, W_u);

    k_params<<<1, 128, 0, stream>>>(W_u, W);

    k_score<<<nblk, TPB, 0, stream>>>(x, n, W, W + OFF_PART, nchunks);

    k_final<<<1, 128, 0, stream>>>(W, W + OFF_PART, nblk, out);
}

// Round 2
// 203.631 us; speedup vs baseline: 1.8964x; 1.8964x over previous
//
#include <hip/hip_runtime.h>
#include <stdint.h>

#define TPB 256
#define MMB 1024        // minmax grid blocks
#define SCB 1024        // score grid blocks
#define WELEM 2048      // elements staged per wave-chunk

// d_ws float layout:
//  [OFF_MM   + 2b]   : minmax block partials {min,max}, b = 0..MMB-1
//  [OFF_PARAMS+ 4k]  : params float4 {inv_s, s, lo=-zp, hi=15-zp}, k = 0..127
//  [OFF_NMIN + k]    : new_min[k]
//  [OFF_NMAX + k]    : new_max[k]
//  [OFF_PART + b*128 + k] : per-score-block partial loss sums
#define OFF_MM     256
#define OFF_PARAMS 2304   // 16B aligned
#define OFF_NMIN   2816
#define OFF_NMAX   2944
#define OFF_PART   4096

__global__ __launch_bounds__(TPB) void k_minmax(const float* __restrict__ x, int n,
                                                float* __restrict__ mm) {
    int n4 = n >> 2;
    const float4* x4 = (const float4*)x;
    float mn = INFINITY, mx = -INFINITY;
    int idx = blockIdx.x * TPB + threadIdx.x;
    int stride = gridDim.x * TPB;
    for (int i = idx; i < n4; i += stride) {
        float4 v = x4[i];
        mn = fminf(mn, fminf(fminf(v.x, v.y), fminf(v.z, v.w)));
        mx = fmaxf(mx, fmaxf(fmaxf(v.x, v.y), fmaxf(v.z, v.w)));
    }
    for (int i = (n4 << 2) + idx; i < n; i += stride) {
        float v = x[i];
        mn = fminf(mn, v);
        mx = fmaxf(mx, v);
    }
    #pragma unroll
    for (int m = 32; m; m >>= 1) {
        mn = fminf(mn, __shfl_xor(mn, m, 64));
        mx = fmaxf(mx, __shfl_xor(mx, m, 64));
    }
    __shared__ float smn[4], smx[4];
    int wv = threadIdx.x >> 6;
    if ((threadIdx.x & 63) == 0) { smn[wv] = mn; smx[wv] = mx; }
    __syncthreads();
    if (threadIdx.x == 0) {
        mn = fminf(fminf(smn[0], smn[1]), fminf(smn[2], smn[3]));
        mx = fmaxf(fmaxf(smx[0], smx[1]), fmaxf(smx[2], smx[3]));
        mm[2 * blockIdx.x + 0] = mn;
        mm[2 * blockIdx.x + 1] = mx;
    }
}

// 1 block, 128 threads: reduce block partials, then candidate k = (i-1)*16 + zp
__global__ void k_params(const float* __restrict__ mm, int mb, float* __restrict__ W) {
    int tid = threadIdx.x;  // 0..127
    float mn = INFINITY, mx = -INFINITY;
    for (int b = tid; b < mb; b += 128) {
        mn = fminf(mn, mm[2 * b + 0]);
        mx = fmaxf(mx, mm[2 * b + 1]);
    }
    #pragma unroll
    for (int m = 32; m; m >>= 1) {
        mn = fminf(mn, __shfl_xor(mn, m, 64));
        mx = fmaxf(mx, __shfl_xor(mx, m, 64));
    }
    __shared__ float smn[2], smx[2];
    int wv = tid >> 6;
    if ((tid & 63) == 0) { smn[wv] = mn; smx[wv] = mx; }
    __syncthreads();
    float xmin = fminf(smn[0], smn[1]);
    float xmax = fmaxf(smx[0], smx[1]);

    int k = tid;
    float xrange = xmax - xmin;
    int ii = k >> 4;                       // 0..7  (i = ii+1)
    float zpf = (float)(k & 15);
    float tmp_max = xrange / 8.0f * (float)(ii + 1);
    float tmp_delta = tmp_max / 15.0f;
    float shift = zpf * tmp_delta;
    float new_min = fmaxf(0.0f - shift, xmin);
    float new_max = fminf(tmp_max - shift, xmax);
    float min_neg = fminf(new_min, 0.0f);
    float max_pos = fmaxf(new_max, 0.0f);
    float scale = fmaxf((max_pos - min_neg) / 15.0f, 1e-8f);
    float zp = 0.0f - rintf(min_neg / scale);
    zp = fminf(fmaxf(zp, 0.0f), 15.0f);
    float4 p;
    p.x = 1.0f / scale;      // inv_s
    p.y = scale;             // s
    p.z = 0.0f - zp;         // lo
    p.w = 15.0f - zp;        // hi
    ((float4*)(W + OFF_PARAMS))[k] = p;
    W[OFF_NMIN + k] = new_min;
    W[OFF_NMAX + k] = new_max;
}

// candidate-per-lane scoring: lane owns candidates 2*lane and 2*lane+1;
// each wave stages a private 2048-elem chunk in LDS, reads it back with
// uniform-address ds_read_b128 (broadcast, conflict-free), accumulates
// both candidates in registers. No cross-lane reduction anywhere.
__global__ __launch_bounds__(TPB) void k_score(const float* __restrict__ x, int n,
                                               const float* __restrict__ W,
                                               float* __restrict__ part) {
    __shared__ float ls[4][WELEM];      // 32 KB, wave-private regions
    __shared__ float wsum[4][128];
    int tid = threadIdx.x, lane = tid & 63, wv = tid >> 6;

    const float4* pg = (const float4*)(W + OFF_PARAMS);
    float4 p0 = pg[2 * lane + 0];
    float4 p1 = pg[2 * lane + 1];
    float a0 = 0.0f, a1 = 0.0f;

    long nl = (long)n;
    int nwc = (int)((nl + WELEM - 1) / WELEM);
    int totW = gridDim.x * 4;
    for (int wc = blockIdx.x * 4 + wv; wc < nwc; wc += totW) {
        long base = (long)wc * WELEM;
        #pragma unroll
        for (int j = 0; j < 8; ++j) {
            long e = base + (long)(j * 64 + lane) * 4;
            float4 v;
            if (e + 3 < nl) {
                v = *(const float4*)(x + e);
            } else {
                v.x = (e + 0 < nl) ? x[e + 0] : 0.0f;  // 0 scores 0 for every candidate
                v.y = (e + 1 < nl) ? x[e + 1] : 0.0f;
                v.z = (e + 2 < nl) ? x[e + 2] : 0.0f;
                v.w = (e + 3 < nl) ? x[e + 3] : 0.0f;
            }
            *(float4*)(&ls[wv][(j * 64 + lane) * 4]) = v;
        }
        // wave-private region: intra-wave write->read ordering only
        asm volatile("s_waitcnt lgkmcnt(0)" ::: "memory");
        __builtin_amdgcn_sched_barrier(0);

        const float4* l4 = (const float4*)(&ls[wv][0]);
        #pragma unroll 4
        for (int i = 0; i < WELEM / 4; ++i) {
            float4 v = l4[i];
            #pragma unroll
            for (int q = 0; q < 4; ++q) {
                float xv = (q == 0) ? v.x : (q == 1) ? v.y : (q == 2) ? v.z : v.w;
                float t0 = xv * p0.x;
                float r0 = rintf(t0);
                float c0 = __builtin_amdgcn_fmed3f(r0, p0.z, p0.w);
                float d0 = __builtin_fmaf(c0, p0.y, -xv);
                a0 = __builtin_fmaf(d0, d0, a0);
                float t1 = xv * p1.x;
                float r1 = rintf(t1);
                float c1 = __builtin_amdgcn_fmed3f(r1, p1.z, p1.w);
                float d1 = __builtin_fmaf(c1, p1.y, -xv);
                a1 = __builtin_fmaf(d1, d1, a1);
            }
        }
    }
    wsum[wv][2 * lane + 0] = a0;
    wsum[wv][2 * lane + 1] = a1;
    __syncthreads();
    if (tid < 128) {
        part[(long)blockIdx.x * 128 + tid] =
            (wsum[0][tid] + wsum[1][tid]) + (wsum[2][tid] + wsum[3][tid]);
    }
}

// 1 block, 128 threads: fixed-order sum over block partials + strict-< argmin
__global__ void k_final(const float* __restrict__ W, const float* __restrict__ part,
                        int nblk, float* __restrict__ out) {
    __shared__ float sc[128];
    int k = threadIdx.x;
    if (k < 128) {
        float s0 = 0.0f, s1 = 0.0f, s2 = 0.0f, s3 = 0.0f;
        int b = 0;
        for (; b + 4 <= nblk; b += 4) {
            s0 += part[(long)(b + 0) * 128 + k];
            s1 += part[(long)(b + 1) * 128 + k];
            s2 += part[(long)(b + 2) * 128 + k];
            s3 += part[(long)(b + 3) * 128 + k];
        }
        float s = (s0 + s1) + (s2 + s3);
        for (; b < nblk; ++b) s += part[(long)b * 128 + k];
        sc[k] = s;
    }
    __syncthreads();
    if (k == 0) {
        int best = 0;
        float bs = sc[0];
        for (int j = 1; j < 128; ++j) {
            if (sc[j] < bs) { bs = sc[j]; best = j; }  // strict < == first occurrence
        }
        out[0] = W[OFF_NMIN + best];
        out[1] = W[OFF_NMAX + best];
    }
}

extern "C" void kernel_launch(void* const* d_in, const int* in_sizes, int n_in,
                              void* d_out, int out_size, void* d_ws, size_t ws_size,
                              hipStream_t stream) {
    const float* x = (const float*)d_in[0];
    int n = in_sizes[0];
    float* out = (float*)d_out;
    float* W = (float*)d_ws;

    // minmax grid
    int n4 = n >> 2;
    int mmb = (n4 + TPB - 1) / TPB;
    if (mmb > MMB) mmb = MMB;
    if (mmb < 1) mmb = 1;

    // score grid (bounded by workspace capacity for partials)
    long maxblk_l = ((long)(ws_size / 4) - OFF_PART) / 128;
    int scb = SCB;
    if (maxblk_l < (long)scb) scb = (int)(maxblk_l < 1 ? 1 : maxblk_l);
    int nwc = (n + WELEM - 1) / WELEM;
    int minblk = (nwc + 3) / 4;
    if (scb > minblk) scb = minblk;   // no empty blocks
    if (scb < 1) scb = 1;

    k_minmax<<<mmb, TPB, 0, stream>>>(x, n, W + OFF_MM);
    k_params<<<1, 128, 0, stream>>>(W + OFF_MM, mmb, W);
    k_score<<<scb, TPB, 0, stream>>>(x, n, W, W + OFF_PART);
    k_final<<<1, 128, 0, stream>>>(W, W + OFF_PART, scb, out);
}

// Round 3
// 166.248 us; speedup vs baseline: 2.3228x; 1.2249x over previous
//
#include <hip/hip_runtime.h>
#include <stdint.h>

#define TPB 256
#define MMB 1024        // minmax grid blocks
#define SCB 1024        // score grid blocks
#define WELEM 2048      // elements per wave-chunk
#define NG (WELEM / 32) // 32-elem groups per chunk

// d_ws float layout:
//  [OFF_MM   + 2b]   : minmax block partials {min,max}, b = 0..MMB-1
//  [OFF_PARAMS+ 4k]  : params float4 {inv_s, s, lo=-zp, hi=15-zp}, k = 0..127
//  [OFF_NMIN + k]    : new_min[k]
//  [OFF_NMAX + k]    : new_max[k]
//  [OFF_PART + b*128 + k] : per-score-block partial loss sums
#define OFF_MM     256
#define OFF_PARAMS 2304   // 16B aligned
#define OFF_NMIN   2816
#define OFF_NMAX   2944
#define OFF_PART   4096

__global__ __launch_bounds__(TPB) void k_minmax(const float* __restrict__ x, int n,
                                                float* __restrict__ mm) {
    int n4 = n >> 2;
    const float4* x4 = (const float4*)x;
    float mn = INFINITY, mx = -INFINITY;
    int idx = blockIdx.x * TPB + threadIdx.x;
    int stride = gridDim.x * TPB;
    for (int i = idx; i < n4; i += stride) {
        float4 v = x4[i];
        mn = fminf(mn, fminf(fminf(v.x, v.y), fminf(v.z, v.w)));
        mx = fmaxf(mx, fmaxf(fmaxf(v.x, v.y), fmaxf(v.z, v.w)));
    }
    for (int i = (n4 << 2) + idx; i < n; i += stride) {
        float v = x[i];
        mn = fminf(mn, v);
        mx = fmaxf(mx, v);
    }
    #pragma unroll
    for (int m = 32; m; m >>= 1) {
        mn = fminf(mn, __shfl_xor(mn, m, 64));
        mx = fmaxf(mx, __shfl_xor(mx, m, 64));
    }
    __shared__ float smn[4], smx[4];
    int wv = threadIdx.x >> 6;
    if ((threadIdx.x & 63) == 0) { smn[wv] = mn; smx[wv] = mx; }
    __syncthreads();
    if (threadIdx.x == 0) {
        mn = fminf(fminf(smn[0], smn[1]), fminf(smn[2], smn[3]));
        mx = fmaxf(fmaxf(smx[0], smx[1]), fmaxf(smx[2], smx[3]));
        mm[2 * blockIdx.x + 0] = mn;
        mm[2 * blockIdx.x + 1] = mx;
    }
}

// 1 block, 128 threads: reduce block partials, then candidate k = (i-1)*16 + zp
__global__ void k_params(const float* __restrict__ mm, int mb, float* __restrict__ W) {
    int tid = threadIdx.x;  // 0..127
    float mn = INFINITY, mx = -INFINITY;
    for (int b = tid; b < mb; b += 128) {
        mn = fminf(mn, mm[2 * b + 0]);
        mx = fmaxf(mx, mm[2 * b + 1]);
    }
    #pragma unroll
    for (int m = 32; m; m >>= 1) {
        mn = fminf(mn, __shfl_xor(mn, m, 64));
        mx = fmaxf(mx, __shfl_xor(mx, m, 64));
    }
    __shared__ float smn[2], smx[2];
    int wv = tid >> 6;
    if ((tid & 63) == 0) { smn[wv] = mn; smx[wv] = mx; }
    __syncthreads();
    float xmin = fminf(smn[0], smn[1]);
    float xmax = fmaxf(smx[0], smx[1]);

    int k = tid;
    float xrange = xmax - xmin;
    int ii = k >> 4;                       // 0..7  (i = ii+1)
    float zpf = (float)(k & 15);
    float tmp_max = xrange / 8.0f * (float)(ii + 1);
    float tmp_delta = tmp_max / 15.0f;
    float shift = zpf * tmp_delta;
    float new_min = fmaxf(0.0f - shift, xmin);
    float new_max = fminf(tmp_max - shift, xmax);
    float min_neg = fminf(new_min, 0.0f);
    float max_pos = fmaxf(new_max, 0.0f);
    float scale = fmaxf((max_pos - min_neg) / 15.0f, 1e-8f);
    float zp = 0.0f - rintf(min_neg / scale);
    zp = fminf(fmaxf(zp, 0.0f), 15.0f);
    float4 p;
    p.x = 1.0f / scale;      // inv_s
    p.y = scale;             // s
    p.z = 0.0f - zp;         // lo
    p.w = 15.0f - zp;        // hi
    ((float4*)(W + OFF_PARAMS))[k] = p;
    W[OFF_NMIN + k] = new_min;
    W[OFF_NMAX + k] = new_max;
}

#define QUANT1(xv) { \
    float t0_ = (xv) * p0.x; float r0_ = rintf(t0_); \
    float c0_ = __builtin_amdgcn_fmed3f(r0_, p0.z, p0.w); \
    float d0_ = __builtin_fmaf(c0_, p0.y, -(xv)); \
    a0 = __builtin_fmaf(d0_, d0_, a0); \
    float t1_ = (xv) * p1.x; float r1_ = rintf(t1_); \
    float c1_ = __builtin_amdgcn_fmed3f(r1_, p1.z, p1.w); \
    float d1_ = __builtin_fmaf(c1_, p1.y, -(xv)); \
    a1 = __builtin_fmaf(d1_, d1_, a1); }
#define QUANT4(V) { QUANT1(V.x) QUANT1(V.y) QUANT1(V.z) QUANT1(V.w) }
#define COMP8(V0,V1,V2,V3,V4,V5,V6,V7) { QUANT4(V0) QUANT4(V1) QUANT4(V2) QUANT4(V3) \
                                         QUANT4(V4) QUANT4(V5) QUANT4(V6) QUANT4(V7) }
#define LOAD8(P,V0,V1,V2,V3,V4,V5,V6,V7) { V0=(P)[0];V1=(P)[1];V2=(P)[2];V3=(P)[3]; \
                                           V4=(P)[4];V5=(P)[5];V6=(P)[6];V7=(P)[7]; }

// candidate-per-lane scoring, no LDS staging: each wave owns whole chunks and
// reads them with wave-uniform global loads (hardware broadcasts one 16B fetch
// to all 64 lanes). Ping-pong register buffers (32 elems) prefetch 1 group
// ahead; lane accumulates candidates 2*lane, 2*lane+1 in registers.
__global__ __launch_bounds__(TPB, 4) void k_score(const float* __restrict__ x, int n,
                                                  const float* __restrict__ W,
                                                  float* __restrict__ part, int nwc) {
    __shared__ float wsum[4][128];
    int tid = threadIdx.x, lane = tid & 63;
    int wv = __builtin_amdgcn_readfirstlane(threadIdx.x >> 6);

    const float4* pg = (const float4*)(W + OFF_PARAMS);
    float4 p0 = pg[2 * lane + 0];
    float4 p1 = pg[2 * lane + 1];
    float a0 = 0.0f, a1 = 0.0f;
    long nl = (long)n;

    for (int wc = blockIdx.x * 4 + wv; wc < nwc; wc += gridDim.x * 4) {
        long base = (long)wc * WELEM;
        if (base + WELEM <= nl) {
            const float4* __restrict__ xp = (const float4*)(x + base);
            float4 A0,A1,A2,A3,A4,A5,A6,A7;
            float4 B0,B1,B2,B3,B4,B5,B6,B7;
            LOAD8(xp, A0,A1,A2,A3,A4,A5,A6,A7)
            #pragma unroll 1
            for (int g = 0; g < NG; g += 2) {
                const float4* q1 = xp + (g + 1) * 8;
                LOAD8(q1, B0,B1,B2,B3,B4,B5,B6,B7)
                COMP8(A0,A1,A2,A3,A4,A5,A6,A7)
                int g2 = (g + 2 < NG) ? (g + 2) : (NG - 1);  // harmless reload on last iter
                const float4* q2 = xp + g2 * 8;
                LOAD8(q2, A0,A1,A2,A3,A4,A5,A6,A7)
                COMP8(B0,B1,B2,B3,B4,B5,B6,B7)
            }
        } else {
            // tail chunk: guarded scalar loads (pad with 0 — scores 0 everywhere)
            for (long e = base; e < base + WELEM; ++e) {
                float xv = (e < nl) ? x[e] : 0.0f;
                QUANT1(xv)
            }
        }
    }
    wsum[wv][2 * lane + 0] = a0;
    wsum[wv][2 * lane + 1] = a1;
    __syncthreads();
    if (tid < 128) {
        part[(long)blockIdx.x * 128 + tid] =
            (wsum[0][tid] + wsum[1][tid]) + (wsum[2][tid] + wsum[3][tid]);
    }
}

// 1 block, 1024 threads: parallel deterministic reduce of partials + argmin.
// candidate k = t>>3, slice j = t&7; fixed-order per-slice sums + fixed tree,
// then uint64 (score_bits<<32 | k) min-reduce — ties pick lowest k (== strict-<
// first-occurrence argmin).
__global__ void k_final(const float* __restrict__ W, const float* __restrict__ part,
                        int nblk, float* __restrict__ out) {
    __shared__ float sjs[128][8];
    __shared__ float sc[128];
    __shared__ unsigned long long wmin[16];
    int t = threadIdx.x;
    int k = t >> 3, j = t & 7;
    float s = 0.0f;
    for (int b = j; b < nblk; b += 8) s += part[(long)b * 128 + k];
    sjs[k][j] = s;
    __syncthreads();
    if (j == 0) {
        sc[k] = ((sjs[k][0] + sjs[k][1]) + (sjs[k][2] + sjs[k][3]))
              + ((sjs[k][4] + sjs[k][5]) + (sjs[k][6] + sjs[k][7]));
    }
    __syncthreads();
    unsigned long long key = ~0ull;
    if (t < 128) {
        key = (((unsigned long long)__float_as_uint(sc[t])) << 32) | (unsigned)t;
    }
    #pragma unroll
    for (int m = 32; m; m >>= 1) {
        unsigned long long o = __shfl_xor(key, m, 64);
        key = (o < key) ? o : key;
    }
    int wv = t >> 6;
    if ((t & 63) == 0) wmin[wv] = key;
    __syncthreads();
    if (t == 0) {
        unsigned long long best = wmin[0];
        for (int w = 1; w < 16; ++w) if (wmin[w] < best) best = wmin[w];
        int bk = (int)(best & 0x7fu);
        out[0] = W[OFF_NMIN + bk];
        out[1] = W[OFF_NMAX + bk];
    }
}

extern "C" void kernel_launch(void* const* d_in, const int* in_sizes, int n_in,
                              void* d_out, int out_size, void* d_ws, size_t ws_size,
                              hipStream_t stream) {
    const float* x = (const float*)d_in[0];
    int n = in_sizes[0];
    float* out = (float*)d_out;
    float* W = (float*)d_ws;

    // minmax grid
    int n4 = n >> 2;
    int mmb = (n4 + TPB - 1) / TPB;
    if (mmb > MMB) mmb = MMB;
    if (mmb < 1) mmb = 1;

    // score grid (bounded by workspace capacity for partials)
    long maxblk_l = ((long)(ws_size / 4) - OFF_PART) / 128;
    int scb = SCB;
    if (maxblk_l < (long)scb) scb = (int)(maxblk_l < 1 ? 1 : maxblk_l);
    int nwc = (n + WELEM - 1) / WELEM;
    int minblk = (nwc + 3) / 4;
    if (scb > minblk) scb = minblk;   // no empty blocks
    if (scb < 1) scb = 1;

    k_minmax<<<mmb, TPB, 0, stream>>>(x, n, W + OFF_MM);
    k_params<<<1, 128, 0, stream>>>(W + OFF_MM, mmb, W);
    k_score<<<scb, TPB, 0, stream>>>(x, n, W, W + OFF_PART, nwc);
    k_final<<<1, 1024, 0, stream>>>(W, W + OFF_PART, scb, out);
}